// Round 8
// baseline (979.786 us; speedup 1.0000x reference)
//
#include <hip/hip_runtime.h>

#define NN 100000
#define NE 1600000
#define ET (NE + NN)   // edges + self-loops = 1,700,000
#define SB 196         // scan blocks: 196*512 = 100352 >= NN

// ---- ordered-uint encoding for float atomicMax (bijective, monotone) ----
__device__ __forceinline__ unsigned enc_f32(float v) {
    unsigned b = __float_as_uint(v);
    return b ^ ((b & 0x80000000u) ? 0xFFFFFFFFu : 0x80000000u);
}
__device__ __forceinline__ float dec_f32(unsigned u) {
    unsigned b = (u & 0x80000000u) ? (u ^ 0x80000000u) : ~u;
    return __uint_as_float(b);
}

// ============================ dense layers ============================

__global__ __launch_bounds__(256) void lin_relu2(const float* __restrict__ x,
                                                 const float* __restrict__ W,
                                                 const float* __restrict__ b,
                                                 float* __restrict__ h) {
    __shared__ float Wl[256 * 32];
    int t = threadIdx.x;
    for (int j = 0; j < 8; ++j) {
        int f = t + 256 * j;
        *(float4*)&Wl[f * 4] = *(const float4*)(W + f * 4);
    }
    __syncthreads();

    int row = (blockIdx.x * 256 + t) >> 3;
    int c0  = (t & 7) * 4;
    const float* xr = x + (long long)row * 256;
    float4 acc = {0.f, 0.f, 0.f, 0.f};
    for (int k4 = 0; k4 < 64; ++k4) {
        float4 xv = *(const float4*)(xr + k4 * 4);
        float4 w0 = *(const float4*)&Wl[(k4 * 4 + 0) * 32 + c0];
        float4 w1 = *(const float4*)&Wl[(k4 * 4 + 1) * 32 + c0];
        float4 w2 = *(const float4*)&Wl[(k4 * 4 + 2) * 32 + c0];
        float4 w3 = *(const float4*)&Wl[(k4 * 4 + 3) * 32 + c0];
        acc.x += xv.x * w0.x + xv.y * w1.x + xv.z * w2.x + xv.w * w3.x;
        acc.y += xv.x * w0.y + xv.y * w1.y + xv.z * w2.y + xv.w * w3.y;
        acc.z += xv.x * w0.z + xv.y * w1.z + xv.z * w2.z + xv.w * w3.z;
        acc.w += xv.x * w0.w + xv.y * w1.w + xv.z * w2.w + xv.w * w3.w;
    }
    float4 bv = *(const float4*)(b + c0);
    acc.x = fmaxf(acc.x + bv.x, 0.f);
    acc.y = fmaxf(acc.y + bv.y, 0.f);
    acc.z = fmaxf(acc.z + bv.z, 0.f);
    acc.w = fmaxf(acc.w + bv.w, 0.f);
    *(float4*)(h + (long long)row * 32 + c0) = acc;
}

// 128 rows/block; thread = 16 rows x 4 cols. hin tile in LDS (wave-broadcast reads).
template<int K>
__global__ __launch_bounds__(256) void gemm_att3(const float* __restrict__ hin,
                                                 const float* __restrict__ W,
                                                 const float* __restrict__ asrc,
                                                 const float* __restrict__ adst,
                                                 float* __restrict__ hp,
                                                 float* __restrict__ es,
                                                 float* __restrict__ ed) {
    __shared__ float hl[128 * K];
    int t = threadIdx.x;
    int base = blockIdx.x * 128;

    const int F4R = K / 4;
    for (int f = t; f < 128 * F4R; f += 256) {
        int row = f / F4R;
        int kq  = f % F4R;
        int gr  = base + row;
        float4 v = {0.f, 0.f, 0.f, 0.f};
        if (gr < NN) v = *(const float4*)(hin + (long long)gr * K + kq * 4);
        *(float4*)&hl[row * K + kq * 4] = v;
    }
    __syncthreads();

    int cg = t & 31, c0 = cg * 4;
    int rq = t >> 5, r0 = rq * 16;
    float4 acc[16];
    #pragma unroll
    for (int i = 0; i < 16; ++i) acc[i] = make_float4(0.f, 0.f, 0.f, 0.f);

    for (int k4 = 0; k4 < K / 4; ++k4) {
        float4 w0 = *(const float4*)(W + (k4 * 4 + 0) * 128 + c0);
        float4 w1 = *(const float4*)(W + (k4 * 4 + 1) * 128 + c0);
        float4 w2 = *(const float4*)(W + (k4 * 4 + 2) * 128 + c0);
        float4 w3 = *(const float4*)(W + (k4 * 4 + 3) * 128 + c0);
        #pragma unroll
        for (int i = 0; i < 16; ++i) {
            float4 hv = *(const float4*)&hl[(r0 + i) * K + k4 * 4];
            acc[i].x += hv.x * w0.x + hv.y * w1.x + hv.z * w2.x + hv.w * w3.x;
            acc[i].y += hv.x * w0.y + hv.y * w1.y + hv.z * w2.y + hv.w * w3.y;
            acc[i].z += hv.x * w0.z + hv.y * w1.z + hv.z * w2.z + hv.w * w3.z;
            acc[i].w += hv.x * w0.w + hv.y * w1.w + hv.z * w2.w + hv.w * w3.w;
        }
    }

    int head = cg >> 3;
    int d0 = (cg & 7) * 4;
    float4 as4 = *(const float4*)(asrc + head * 32 + d0);
    float4 ad4 = *(const float4*)(adst + head * 32 + d0);
    #pragma unroll
    for (int i = 0; i < 16; ++i) {
        int gr = base + r0 + i;
        if (gr >= NN) break;
        *(float4*)(hp + (long long)gr * 128 + c0) = acc[i];
        float ps = acc[i].x * as4.x + acc[i].y * as4.y + acc[i].z * as4.z + acc[i].w * as4.w;
        float pd = acc[i].x * ad4.x + acc[i].y * ad4.y + acc[i].z * ad4.z + acc[i].w * ad4.w;
        for (int off = 1; off < 8; off <<= 1) {
            ps += __shfl_xor(ps, off, 8);
            pd += __shfl_xor(pd, off, 8);
        }
        if ((cg & 7) == 0) {
            es[gr * 4 + head] = ps;
            ed[gr * 4 + head] = pd;
        }
    }
}

// ============================ CSR build (once) ============================

__global__ void count_deg(const int* __restrict__ ei, int* __restrict__ deg) {
    int e = blockIdx.x * 256 + threadIdx.x;
    if (e >= ET) return;
    int dst = (e < NE) ? ei[NE + e] : e - NE;
    atomicAdd(deg + dst, 1);
}

__global__ __launch_bounds__(256) void scan1(const int* __restrict__ deg,
                                             int* __restrict__ tpre,
                                             int* __restrict__ bsum) {
    __shared__ int ls[256];
    int t = threadIdx.x, b = blockIdx.x;
    int i0 = b * 512 + t * 2;
    int d0 = (i0 < NN) ? deg[i0] : 0;
    int d1 = (i0 + 1 < NN) ? deg[i0 + 1] : 0;
    int local = d0 + d1;
    ls[t] = local;
    __syncthreads();
    for (int off = 1; off < 256; off <<= 1) {
        int v = (t >= off) ? ls[t - off] : 0;
        __syncthreads();
        ls[t] += v;
        __syncthreads();
    }
    tpre[b * 256 + t] = ls[t] - local;
    if (t == 255) bsum[b] = ls[255];
}

__global__ __launch_bounds__(256) void scan2(const int* __restrict__ bsum,
                                             int* __restrict__ boff) {
    __shared__ int ls[256];
    int t = threadIdx.x;
    int v = (t < SB) ? bsum[t] : 0;
    ls[t] = v;
    __syncthreads();
    for (int off = 1; off < 256; off <<= 1) {
        int u = (t >= off) ? ls[t - off] : 0;
        __syncthreads();
        ls[t] += u;
        __syncthreads();
    }
    if (t < SB) boff[t] = ls[t] - v;
}

__global__ __launch_bounds__(256) void scan3(const int* __restrict__ deg,
                                             const int* __restrict__ tpre,
                                             const int* __restrict__ boff,
                                             int* __restrict__ row_ptr) {
    int t = threadIdx.x, b = blockIdx.x;
    int i0 = b * 512 + t * 2;
    int p = boff[b] + tpre[b * 256 + t];
    if (i0 < NN)     row_ptr[i0] = p;
    if (i0 + 1 < NN) row_ptr[i0 + 1] = p + deg[i0];
    if (b == 0 && t == 0) row_ptr[NN] = ET;
}

__global__ void fill_csr(const int* __restrict__ ei, int* __restrict__ cursor,
                         int* __restrict__ col) {
    int e = blockIdx.x * 256 + threadIdx.x;
    if (e >= ET) return;
    int src, dst;
    if (e < NE) { src = ei[e]; dst = ei[NE + e]; }
    else        { src = dst = e - NE; }
    int pos = atomicAdd(cursor + dst, 1);
    col[pos] = src;
}

// ============== per-head global max of es/ed -> mx[0..3]=es, mx[4..7]=ed ==============
// mx must be memset to 0 (enc of any finite float is > 0).
__global__ __launch_bounds__(256) void head_max(const float* __restrict__ es,
                                                const float* __restrict__ ed,
                                                unsigned* __restrict__ mx) {
    int tid = blockIdx.x * 256 + threadIdx.x;     // 128*256 = 32768 threads
    float4 ms = {-1e30f, -1e30f, -1e30f, -1e30f};
    float4 md = {-1e30f, -1e30f, -1e30f, -1e30f};
    for (int n = tid; n < NN; n += 32768) {
        float4 a = *(const float4*)(es + n * 4);
        float4 d = *(const float4*)(ed + n * 4);
        ms.x = fmaxf(ms.x, a.x); ms.y = fmaxf(ms.y, a.y);
        ms.z = fmaxf(ms.z, a.z); ms.w = fmaxf(ms.w, a.w);
        md.x = fmaxf(md.x, d.x); md.y = fmaxf(md.y, d.y);
        md.z = fmaxf(md.z, d.z); md.w = fmaxf(md.w, d.w);
    }
    for (int off = 1; off < 64; off <<= 1) {
        ms.x = fmaxf(ms.x, __shfl_xor(ms.x, off));
        ms.y = fmaxf(ms.y, __shfl_xor(ms.y, off));
        ms.z = fmaxf(ms.z, __shfl_xor(ms.z, off));
        ms.w = fmaxf(ms.w, __shfl_xor(ms.w, off));
        md.x = fmaxf(md.x, __shfl_xor(md.x, off));
        md.y = fmaxf(md.y, __shfl_xor(md.y, off));
        md.z = fmaxf(md.z, __shfl_xor(md.z, off));
        md.w = fmaxf(md.w, __shfl_xor(md.w, off));
    }
    if ((threadIdx.x & 63) == 0) {
        atomicMax(mx + 0, enc_f32(ms.x));
        atomicMax(mx + 1, enc_f32(ms.y));
        atomicMax(mx + 2, enc_f32(ms.z));
        atomicMax(mx + 3, enc_f32(ms.w));
        atomicMax(mx + 4, enc_f32(md.x));
        atomicMax(mx + 5, enc_f32(md.y));
        atomicMax(mx + 6, enc_f32(md.z));
        atomicMax(mx + 7, enc_f32(md.w));
    }
}

// ==================== single-pass softmax-aggregate (global shift) ====================
// softmax is shift-invariant for any C >= max logit; C = leaky(max es + max ed) per head.
__global__ void gat_aggregate2(const int* __restrict__ row_ptr, const int* __restrict__ col,
                               const float* __restrict__ es, const float* __restrict__ ed,
                               const unsigned* __restrict__ mx,
                               const float* __restrict__ hp, const float* __restrict__ b,
                               float* __restrict__ out) {
    int tid = blockIdx.x * 256 + threadIdx.x;
    int n = tid >> 5;
    int t = tid & 31;
    if (n >= NN) return;
    int head = t >> 3;
    int beg = row_ptr[n], end = row_ptr[n + 1];

    float Craw = dec_f32(mx[head]) + dec_f32(mx[4 + head]);
    float C = Craw > 0.f ? Craw : 0.2f * Craw;     // leaky is monotone -> valid bound
    float edv = ed[n * 4 + head];

    float4 acc = {0.f, 0.f, 0.f, 0.f};
    float ws = 0.f;
    int i = beg;
    for (; i + 3 < end; i += 4) {
        int s0 = col[i], s1 = col[i + 1], s2 = col[i + 2], s3 = col[i + 3];
        float l0 = es[s0 * 4 + head] + edv;
        float l1 = es[s1 * 4 + head] + edv;
        float l2 = es[s2 * 4 + head] + edv;
        float l3 = es[s3 * 4 + head] + edv;
        float4 h0 = *(const float4*)(hp + (long long)s0 * 128 + t * 4);
        float4 h1 = *(const float4*)(hp + (long long)s1 * 128 + t * 4);
        float4 h2 = *(const float4*)(hp + (long long)s2 * 128 + t * 4);
        float4 h3 = *(const float4*)(hp + (long long)s3 * 128 + t * 4);
        l0 = l0 > 0.f ? l0 : 0.2f * l0;
        l1 = l1 > 0.f ? l1 : 0.2f * l1;
        l2 = l2 > 0.f ? l2 : 0.2f * l2;
        l3 = l3 > 0.f ? l3 : 0.2f * l3;
        float w0 = __expf(l0 - C);
        float w1 = __expf(l1 - C);
        float w2 = __expf(l2 - C);
        float w3 = __expf(l3 - C);
        ws += (w0 + w1) + (w2 + w3);
        acc.x += w0 * h0.x + w1 * h1.x + w2 * h2.x + w3 * h3.x;
        acc.y += w0 * h0.y + w1 * h1.y + w2 * h2.y + w3 * h3.y;
        acc.z += w0 * h0.z + w1 * h1.z + w2 * h2.z + w3 * h3.z;
        acc.w += w0 * h0.w + w1 * h1.w + w2 * h2.w + w3 * h3.w;
    }
    for (; i < end; ++i) {
        int s = col[i];
        float lv = es[s * 4 + head] + edv;
        lv = lv > 0.f ? lv : 0.2f * lv;
        float w = __expf(lv - C);
        ws += w;
        float4 hv = *(const float4*)(hp + (long long)s * 128 + t * 4);
        acc.x += w * hv.x; acc.y += w * hv.y;
        acc.z += w * hv.z; acc.w += w * hv.w;
    }
    float sv = ws + 1e-16f;
    float4 bv = *(const float4*)(b + t * 4);
    float4 v;
    v.x = acc.x / sv + bv.x;
    v.y = acc.y / sv + bv.y;
    v.z = acc.z / sv + bv.z;
    v.w = acc.w / sv + bv.w;
    v.x = v.x > 0.f ? v.x : expm1f(v.x);
    v.y = v.y > 0.f ? v.y : expm1f(v.y);
    v.z = v.z > 0.f ? v.z : expm1f(v.z);
    v.w = v.w > 0.f ? v.w : expm1f(v.w);
    *(float4*)(out + (long long)n * 128 + t * 4) = v;
}

// ============================ host ============================

extern "C" void kernel_launch(void* const* d_in, const int* in_sizes, int n_in,
                              void* d_out, int out_size, void* d_ws, size_t ws_size,
                              hipStream_t stream) {
    const float* x    = (const float*)d_in[0];
    const int*   ei   = (const int*)d_in[1];
    const float* W_in = (const float*)d_in[2];
    const float* b_in = (const float*)d_in[3];
    const float* W[3]  = {(const float*)d_in[4], (const float*)d_in[8],  (const float*)d_in[12]};
    const float* As[3] = {(const float*)d_in[5], (const float*)d_in[9],  (const float*)d_in[13]};
    const float* Ad[3] = {(const float*)d_in[6], (const float*)d_in[10], (const float*)d_in[14]};
    const float* Bs[3] = {(const float*)d_in[7], (const float*)d_in[11], (const float*)d_in[15]};

    // workspace layout (~76 MB); accb aliases d_out
    float* h0     = (float*)d_ws;                       // NN*32
    float* hp     = h0 + (size_t)NN * 32;               // NN*128
    float* es     = hp + (size_t)NN * 128;              // NN*4
    float* ed     = es + (size_t)NN * 4;                // NN*4
    int*   row_ptr= (int*)(ed + (size_t)NN * 4);        // NN+1
    int*   deg    = row_ptr + (NN + 1);                 // NN
    int*   cursor = deg + NN;                           // NN
    int*   tpre   = cursor + NN;                        // SB*256
    int*   bsum   = tpre + SB * 256;                    // SB
    int*   boff   = bsum + SB;                          // SB
    unsigned* mx  = (unsigned*)(boff + SB);             // 8
    int*   colb   = (int*)(mx + 8);                     // ET
    float* accb   = (float*)d_out;                      // NN*128

    // ---- CSR build (graph is static across layers) ----
    hipMemsetAsync(deg, 0, (size_t)NN * sizeof(int), stream);
    count_deg<<<(ET + 255) / 256, 256, 0, stream>>>(ei, deg);
    scan1<<<SB, 256, 0, stream>>>(deg, tpre, bsum);
    scan2<<<1, 256, 0, stream>>>(bsum, boff);
    scan3<<<SB, 256, 0, stream>>>(deg, tpre, boff, row_ptr);
    hipMemcpyAsync(cursor, row_ptr, (size_t)NN * sizeof(int),
                   hipMemcpyDeviceToDevice, stream);
    fill_csr<<<(ET + 255) / 256, 256, 0, stream>>>(ei, cursor, colb);

    lin_relu2<<<3125, 256, 0, stream>>>(x, W_in, b_in, h0);

    const float* in = h0;
    for (int l = 0; l < 3; ++l) {
        if (l == 0)
            gemm_att3<32><<<782, 256, 0, stream>>>(in, W[0], As[0], Ad[0], hp, es, ed);
        else
            gemm_att3<128><<<782, 256, 0, stream>>>(in, W[l], As[l], Ad[l], hp, es, ed);
        hipMemsetAsync(mx, 0, 8 * sizeof(unsigned), stream);
        head_max<<<128, 256, 0, stream>>>(es, ed, mx);
        gat_aggregate2<<<12500, 256, 0, stream>>>(row_ptr, colb, es, ed, mx, hp, Bs[l], accb);
        in = accb;
    }
}

// Round 9
// 667.137 us; speedup vs baseline: 1.4686x; 1.4686x over previous
//
#include <hip/hip_runtime.h>
#include <hip/hip_fp16.h>

#define NN 100000
#define NE 1600000
#define ET (NE + NN)   // edges + self-loops = 1,700,000
#define SB 196         // scan blocks: 196*512 = 100352 >= NN

// ---- ordered-uint encoding for float atomicMax (bijective, monotone) ----
__device__ __forceinline__ unsigned enc_f32(float v) {
    unsigned b = __float_as_uint(v);
    return b ^ ((b & 0x80000000u) ? 0xFFFFFFFFu : 0x80000000u);
}
__device__ __forceinline__ float dec_f32(unsigned u) {
    unsigned b = (u & 0x80000000u) ? (u ^ 0x80000000u) : ~u;
    return __uint_as_float(b);
}

// ============================ dense layers ============================

__global__ __launch_bounds__(256) void lin_relu2(const float* __restrict__ x,
                                                 const float* __restrict__ W,
                                                 const float* __restrict__ b,
                                                 float* __restrict__ h) {
    __shared__ float Wl[256 * 32];
    int t = threadIdx.x;
    for (int j = 0; j < 8; ++j) {
        int f = t + 256 * j;
        *(float4*)&Wl[f * 4] = *(const float4*)(W + f * 4);
    }
    __syncthreads();

    int row = (blockIdx.x * 256 + t) >> 3;
    int c0  = (t & 7) * 4;
    const float* xr = x + (long long)row * 256;
    float4 acc = {0.f, 0.f, 0.f, 0.f};
    for (int k4 = 0; k4 < 64; ++k4) {
        float4 xv = *(const float4*)(xr + k4 * 4);
        float4 w0 = *(const float4*)&Wl[(k4 * 4 + 0) * 32 + c0];
        float4 w1 = *(const float4*)&Wl[(k4 * 4 + 1) * 32 + c0];
        float4 w2 = *(const float4*)&Wl[(k4 * 4 + 2) * 32 + c0];
        float4 w3 = *(const float4*)&Wl[(k4 * 4 + 3) * 32 + c0];
        acc.x += xv.x * w0.x + xv.y * w1.x + xv.z * w2.x + xv.w * w3.x;
        acc.y += xv.x * w0.y + xv.y * w1.y + xv.z * w2.y + xv.w * w3.y;
        acc.z += xv.x * w0.z + xv.y * w1.z + xv.z * w2.z + xv.w * w3.z;
        acc.w += xv.x * w0.w + xv.y * w1.w + xv.z * w2.w + xv.w * w3.w;
    }
    float4 bv = *(const float4*)(b + c0);
    acc.x = fmaxf(acc.x + bv.x, 0.f);
    acc.y = fmaxf(acc.y + bv.y, 0.f);
    acc.z = fmaxf(acc.z + bv.z, 0.f);
    acc.w = fmaxf(acc.w + bv.w, 0.f);
    *(float4*)(h + (long long)row * 32 + c0) = acc;
}

// 128 rows/block; thread = 16 rows x 4 cols. hp stored as FP16.
// Also computes per-head global maxes of es/ed into mxl[0..7] (block LDS reduce).
template<int K>
__global__ __launch_bounds__(256) void gemm_att3(const float* __restrict__ hin,
                                                 const float* __restrict__ W,
                                                 const float* __restrict__ asrc,
                                                 const float* __restrict__ adst,
                                                 __half* __restrict__ hph,
                                                 float* __restrict__ es,
                                                 float* __restrict__ ed,
                                                 unsigned* __restrict__ mxl) {
    __shared__ float hl[128 * K];
    __shared__ unsigned lmx[8];
    int t = threadIdx.x;
    int base = blockIdx.x * 128;

    const int F4R = K / 4;
    for (int f = t; f < 128 * F4R; f += 256) {
        int row = f / F4R;
        int kq  = f % F4R;
        int gr  = base + row;
        float4 v = {0.f, 0.f, 0.f, 0.f};
        if (gr < NN) v = *(const float4*)(hin + (long long)gr * K + kq * 4);
        *(float4*)&hl[row * K + kq * 4] = v;
    }
    if (t < 8) lmx[t] = 0u;
    __syncthreads();

    int cg = t & 31, c0 = cg * 4;
    int rq = t >> 5, r0 = rq * 16;
    float4 acc[16];
    #pragma unroll
    for (int i = 0; i < 16; ++i) acc[i] = make_float4(0.f, 0.f, 0.f, 0.f);

    for (int k4 = 0; k4 < K / 4; ++k4) {
        float4 w0 = *(const float4*)(W + (k4 * 4 + 0) * 128 + c0);
        float4 w1 = *(const float4*)(W + (k4 * 4 + 1) * 128 + c0);
        float4 w2 = *(const float4*)(W + (k4 * 4 + 2) * 128 + c0);
        float4 w3 = *(const float4*)(W + (k4 * 4 + 3) * 128 + c0);
        #pragma unroll
        for (int i = 0; i < 16; ++i) {
            float4 hv = *(const float4*)&hl[(r0 + i) * K + k4 * 4];
            acc[i].x += hv.x * w0.x + hv.y * w1.x + hv.z * w2.x + hv.w * w3.x;
            acc[i].y += hv.x * w0.y + hv.y * w1.y + hv.z * w2.y + hv.w * w3.y;
            acc[i].z += hv.x * w0.z + hv.y * w1.z + hv.z * w2.z + hv.w * w3.z;
            acc[i].w += hv.x * w0.w + hv.y * w1.w + hv.z * w2.w + hv.w * w3.w;
        }
    }

    int head = cg >> 3;
    int d0 = (cg & 7) * 4;
    float4 as4 = *(const float4*)(asrc + head * 32 + d0);
    float4 ad4 = *(const float4*)(adst + head * 32 + d0);
    float smax = -1e30f, dmax = -1e30f;
    #pragma unroll
    for (int i = 0; i < 16; ++i) {
        int gr = base + r0 + i;
        if (gr >= NN) break;
        __half2 p0 = __floats2half2_rn(acc[i].x, acc[i].y);
        __half2 p1 = __floats2half2_rn(acc[i].z, acc[i].w);
        uint2 pk;
        pk.x = *(unsigned*)&p0;
        pk.y = *(unsigned*)&p1;
        *(uint2*)(hph + (long long)gr * 128 + c0) = pk;
        float ps = acc[i].x * as4.x + acc[i].y * as4.y + acc[i].z * as4.z + acc[i].w * as4.w;
        float pd = acc[i].x * ad4.x + acc[i].y * ad4.y + acc[i].z * ad4.z + acc[i].w * ad4.w;
        for (int off = 1; off < 8; off <<= 1) {
            ps += __shfl_xor(ps, off, 8);
            pd += __shfl_xor(pd, off, 8);
        }
        if ((cg & 7) == 0) {
            es[gr * 4 + head] = ps;
            ed[gr * 4 + head] = pd;
            smax = fmaxf(smax, ps);
            dmax = fmaxf(dmax, pd);
        }
    }
    if ((cg & 7) == 0) {
        atomicMax(&lmx[head], enc_f32(smax));
        atomicMax(&lmx[4 + head], enc_f32(dmax));
    }
    __syncthreads();
    if (t < 8) atomicMax(mxl + t, lmx[t]);
}

// ============================ CSR build (once) ============================

__global__ void count_deg(const int* __restrict__ ei, int* __restrict__ deg) {
    int e = blockIdx.x * 256 + threadIdx.x;
    if (e >= ET) return;
    int dst = (e < NE) ? ei[NE + e] : e - NE;
    atomicAdd(deg + dst, 1);
}

__global__ __launch_bounds__(256) void scan1(const int* __restrict__ deg,
                                             int* __restrict__ tpre,
                                             int* __restrict__ bsum) {
    __shared__ int ls[256];
    int t = threadIdx.x, b = blockIdx.x;
    int i0 = b * 512 + t * 2;
    int d0 = (i0 < NN) ? deg[i0] : 0;
    int d1 = (i0 + 1 < NN) ? deg[i0 + 1] : 0;
    int local = d0 + d1;
    ls[t] = local;
    __syncthreads();
    for (int off = 1; off < 256; off <<= 1) {
        int v = (t >= off) ? ls[t - off] : 0;
        __syncthreads();
        ls[t] += v;
        __syncthreads();
    }
    tpre[b * 256 + t] = ls[t] - local;
    if (t == 255) bsum[b] = ls[255];
}

__global__ __launch_bounds__(256) void scan2(const int* __restrict__ bsum,
                                             int* __restrict__ boff) {
    __shared__ int ls[256];
    int t = threadIdx.x;
    int v = (t < SB) ? bsum[t] : 0;
    ls[t] = v;
    __syncthreads();
    for (int off = 1; off < 256; off <<= 1) {
        int u = (t >= off) ? ls[t - off] : 0;
        __syncthreads();
        ls[t] += u;
        __syncthreads();
    }
    if (t < SB) boff[t] = ls[t] - v;
}

__global__ __launch_bounds__(256) void scan3(const int* __restrict__ deg,
                                             const int* __restrict__ tpre,
                                             const int* __restrict__ boff,
                                             int* __restrict__ row_ptr) {
    int t = threadIdx.x, b = blockIdx.x;
    int i0 = b * 512 + t * 2;
    int p = boff[b] + tpre[b * 256 + t];
    if (i0 < NN)     row_ptr[i0] = p;
    if (i0 + 1 < NN) row_ptr[i0 + 1] = p + deg[i0];
    if (b == 0 && t == 0) row_ptr[NN] = ET;
}

__global__ void fill_csr(const int* __restrict__ ei, int* __restrict__ cursor,
                         int* __restrict__ col) {
    int e = blockIdx.x * 256 + threadIdx.x;
    if (e >= ET) return;
    int src, dst;
    if (e < NE) { src = ei[e]; dst = ei[NE + e]; }
    else        { src = dst = e - NE; }
    int pos = atomicAdd(cursor + dst, 1);
    col[pos] = src;
}

// ==================== single-pass softmax-aggregate (fp16 gather) ====================
// 16 lanes/node, each lane owns 8 dims (one 16B uint4 = 8 halves per edge).
// softmax shift C = leaky(max es + max ed) per head (valid global upper bound).
__global__ __launch_bounds__(256) void gat_aggregate3(
        const int* __restrict__ row_ptr, const int* __restrict__ col,
        const float* __restrict__ es, const float* __restrict__ ed,
        const unsigned* __restrict__ mx, const __half* __restrict__ hph,
        const float* __restrict__ b, float* __restrict__ out) {
    int tid = blockIdx.x * 256 + threadIdx.x;
    int n = tid >> 4;
    int t = tid & 15;
    if (n >= NN) return;
    int head = t >> 2;
    int beg = row_ptr[n], end = row_ptr[n + 1];

    float Craw = dec_f32(mx[head]) + dec_f32(mx[4 + head]);
    float C = Craw > 0.f ? Craw : 0.2f * Craw;
    float edv = ed[n * 4 + head];

    float acc[8] = {0.f, 0.f, 0.f, 0.f, 0.f, 0.f, 0.f, 0.f};
    float ws = 0.f;
    const __half* hb = hph + (long long)t * 8;

    int i = beg;
    for (; i + 3 < end; i += 4) {
        int s0 = col[i], s1 = col[i + 1], s2 = col[i + 2], s3 = col[i + 3];
        float l0 = es[s0 * 4 + head] + edv;
        float l1 = es[s1 * 4 + head] + edv;
        float l2 = es[s2 * 4 + head] + edv;
        float l3 = es[s3 * 4 + head] + edv;
        uint4 g0 = *(const uint4*)(hb + (long long)s0 * 128);
        uint4 g1 = *(const uint4*)(hb + (long long)s1 * 128);
        uint4 g2 = *(const uint4*)(hb + (long long)s2 * 128);
        uint4 g3 = *(const uint4*)(hb + (long long)s3 * 128);
        l0 = l0 > 0.f ? l0 : 0.2f * l0;
        l1 = l1 > 0.f ? l1 : 0.2f * l1;
        l2 = l2 > 0.f ? l2 : 0.2f * l2;
        l3 = l3 > 0.f ? l3 : 0.2f * l3;
        float w0 = __expf(l0 - C);
        float w1 = __expf(l1 - C);
        float w2 = __expf(l2 - C);
        float w3 = __expf(l3 - C);
        ws += (w0 + w1) + (w2 + w3);
        float2 f;
        f = __half22float2(*(__half2*)&g0.x); acc[0] += w0 * f.x; acc[1] += w0 * f.y;
        f = __half22float2(*(__half2*)&g0.y); acc[2] += w0 * f.x; acc[3] += w0 * f.y;
        f = __half22float2(*(__half2*)&g0.z); acc[4] += w0 * f.x; acc[5] += w0 * f.y;
        f = __half22float2(*(__half2*)&g0.w); acc[6] += w0 * f.x; acc[7] += w0 * f.y;
        f = __half22float2(*(__half2*)&g1.x); acc[0] += w1 * f.x; acc[1] += w1 * f.y;
        f = __half22float2(*(__half2*)&g1.y); acc[2] += w1 * f.x; acc[3] += w1 * f.y;
        f = __half22float2(*(__half2*)&g1.z); acc[4] += w1 * f.x; acc[5] += w1 * f.y;
        f = __half22float2(*(__half2*)&g1.w); acc[6] += w1 * f.x; acc[7] += w1 * f.y;
        f = __half22float2(*(__half2*)&g2.x); acc[0] += w2 * f.x; acc[1] += w2 * f.y;
        f = __half22float2(*(__half2*)&g2.y); acc[2] += w2 * f.x; acc[3] += w2 * f.y;
        f = __half22float2(*(__half2*)&g2.z); acc[4] += w2 * f.x; acc[5] += w2 * f.y;
        f = __half22float2(*(__half2*)&g2.w); acc[6] += w2 * f.x; acc[7] += w2 * f.y;
        f = __half22float2(*(__half2*)&g3.x); acc[0] += w3 * f.x; acc[1] += w3 * f.y;
        f = __half22float2(*(__half2*)&g3.y); acc[2] += w3 * f.x; acc[3] += w3 * f.y;
        f = __half22float2(*(__half2*)&g3.z); acc[4] += w3 * f.x; acc[5] += w3 * f.y;
        f = __half22float2(*(__half2*)&g3.w); acc[6] += w3 * f.x; acc[7] += w3 * f.y;
    }
    for (; i < end; ++i) {
        int s = col[i];
        float lv = es[s * 4 + head] + edv;
        lv = lv > 0.f ? lv : 0.2f * lv;
        float w = __expf(lv - C);
        ws += w;
        uint4 g = *(const uint4*)(hb + (long long)s * 128);
        float2 f;
        f = __half22float2(*(__half2*)&g.x); acc[0] += w * f.x; acc[1] += w * f.y;
        f = __half22float2(*(__half2*)&g.y); acc[2] += w * f.x; acc[3] += w * f.y;
        f = __half22float2(*(__half2*)&g.z); acc[4] += w * f.x; acc[5] += w * f.y;
        f = __half22float2(*(__half2*)&g.w); acc[6] += w * f.x; acc[7] += w * f.y;
    }
    float sv = ws + 1e-16f;
    float4 b0 = *(const float4*)(b + t * 8);
    float4 b1 = *(const float4*)(b + t * 8 + 4);
    float4 v0, v1;
    v0.x = acc[0] / sv + b0.x; v0.y = acc[1] / sv + b0.y;
    v0.z = acc[2] / sv + b0.z; v0.w = acc[3] / sv + b0.w;
    v1.x = acc[4] / sv + b1.x; v1.y = acc[5] / sv + b1.y;
    v1.z = acc[6] / sv + b1.z; v1.w = acc[7] / sv + b1.w;
    v0.x = v0.x > 0.f ? v0.x : expm1f(v0.x);
    v0.y = v0.y > 0.f ? v0.y : expm1f(v0.y);
    v0.z = v0.z > 0.f ? v0.z : expm1f(v0.z);
    v0.w = v0.w > 0.f ? v0.w : expm1f(v0.w);
    v1.x = v1.x > 0.f ? v1.x : expm1f(v1.x);
    v1.y = v1.y > 0.f ? v1.y : expm1f(v1.y);
    v1.z = v1.z > 0.f ? v1.z : expm1f(v1.z);
    v1.w = v1.w > 0.f ? v1.w : expm1f(v1.w);
    *(float4*)(out + (long long)n * 128 + t * 8) = v0;
    *(float4*)(out + (long long)n * 128 + t * 8 + 4) = v1;
}

// ============================ host ============================

extern "C" void kernel_launch(void* const* d_in, const int* in_sizes, int n_in,
                              void* d_out, int out_size, void* d_ws, size_t ws_size,
                              hipStream_t stream) {
    const float* x    = (const float*)d_in[0];
    const int*   ei   = (const int*)d_in[1];
    const float* W_in = (const float*)d_in[2];
    const float* b_in = (const float*)d_in[3];
    const float* W[3]  = {(const float*)d_in[4], (const float*)d_in[8],  (const float*)d_in[12]};
    const float* As[3] = {(const float*)d_in[5], (const float*)d_in[9],  (const float*)d_in[13]};
    const float* Ad[3] = {(const float*)d_in[6], (const float*)d_in[10], (const float*)d_in[14]};
    const float* Bs[3] = {(const float*)d_in[7], (const float*)d_in[11], (const float*)d_in[15]};

    // workspace layout (~50 MB); accb aliases d_out
    float*  h0     = (float*)d_ws;                      // NN*32 f32
    __half* hph    = (__half*)(h0 + (size_t)NN * 32);   // NN*128 f16
    float*  es     = (float*)(hph + (size_t)NN * 128);  // NN*4
    float*  ed     = es + (size_t)NN * 4;               // NN*4
    int*    row_ptr= (int*)(ed + (size_t)NN * 4);       // NN+1
    int*    deg    = row_ptr + (NN + 1);                // NN
    int*    cursor = deg + NN;                          // NN
    int*    tpre   = cursor + NN;                       // SB*256
    int*    bsum   = tpre + SB * 256;                   // SB
    int*    boff   = bsum + SB;                         // SB
    unsigned* mx   = (unsigned*)(boff + SB);            // 24 (8 per layer)
    int*    colb   = (int*)(mx + 24);                   // ET
    float*  accb   = (float*)d_out;                     // NN*128 f32

    // ---- CSR build (graph is static across layers); zero all 3 layers' mx ----
    hipMemsetAsync(deg, 0, (size_t)NN * sizeof(int), stream);
    hipMemsetAsync(mx, 0, 24 * sizeof(unsigned), stream);
    count_deg<<<(ET + 255) / 256, 256, 0, stream>>>(ei, deg);
    scan1<<<SB, 256, 0, stream>>>(deg, tpre, bsum);
    scan2<<<1, 256, 0, stream>>>(bsum, boff);
    scan3<<<SB, 256, 0, stream>>>(deg, tpre, boff, row_ptr);
    hipMemcpyAsync(cursor, row_ptr, (size_t)NN * sizeof(int),
                   hipMemcpyDeviceToDevice, stream);
    fill_csr<<<(ET + 255) / 256, 256, 0, stream>>>(ei, cursor, colb);

    lin_relu2<<<3125, 256, 0, stream>>>(x, W_in, b_in, h0);

    const float* in = h0;
    for (int l = 0; l < 3; ++l) {
        if (l == 0)
            gemm_att3<32><<<782, 256, 0, stream>>>(in, W[0], As[0], Ad[0], hph, es, ed, mx);
        else
            gemm_att3<128><<<782, 256, 0, stream>>>(in, W[l], As[l], Ad[l], hph, es, ed, mx + l * 8);
        gat_aggregate3<<<6250, 256, 0, stream>>>(row_ptr, colb, es, ed, mx + l * 8, hph, Bs[l], accb);
        in = accb;
    }
}

// Round 10
// 557.081 us; speedup vs baseline: 1.7588x; 1.1976x over previous
//
#include <hip/hip_runtime.h>
#include <hip/hip_fp16.h>

#define NN 100000
#define NE 1600000
#define ET (NE + NN)   // edges + self-loops = 1,700,000
#define BKW 512                      // bucket width (nodes); dst>>9
#define NBK ((NN + BKW - 1) / BKW)   // 196 buckets
#define LCOL_CAP 12288               // max edges/bucket (mean 8704, sigma ~93)
#define EPB 16384                    // edges per scatter block

// ---- ordered-uint encoding for float atomicMax (bijective, monotone) ----
__device__ __forceinline__ unsigned enc_f32(float v) {
    unsigned b = __float_as_uint(v);
    return b ^ ((b & 0x80000000u) ? 0xFFFFFFFFu : 0x80000000u);
}
__device__ __forceinline__ float dec_f32(unsigned u) {
    unsigned b = (u & 0x80000000u) ? (u ^ 0x80000000u) : ~u;
    return __uint_as_float(b);
}

// ============================ dense layers ============================

__global__ __launch_bounds__(256) void lin_relu2(const float* __restrict__ x,
                                                 const float* __restrict__ W,
                                                 const float* __restrict__ b,
                                                 float* __restrict__ h) {
    __shared__ float Wl[256 * 32];
    int t = threadIdx.x;
    for (int j = 0; j < 8; ++j) {
        int f = t + 256 * j;
        *(float4*)&Wl[f * 4] = *(const float4*)(W + f * 4);
    }
    __syncthreads();

    int row = (blockIdx.x * 256 + t) >> 3;
    int c0  = (t & 7) * 4;
    const float* xr = x + (long long)row * 256;
    float4 acc = {0.f, 0.f, 0.f, 0.f};
    for (int k4 = 0; k4 < 64; ++k4) {
        float4 xv = *(const float4*)(xr + k4 * 4);
        float4 w0 = *(const float4*)&Wl[(k4 * 4 + 0) * 32 + c0];
        float4 w1 = *(const float4*)&Wl[(k4 * 4 + 1) * 32 + c0];
        float4 w2 = *(const float4*)&Wl[(k4 * 4 + 2) * 32 + c0];
        float4 w3 = *(const float4*)&Wl[(k4 * 4 + 3) * 32 + c0];
        acc.x += xv.x * w0.x + xv.y * w1.x + xv.z * w2.x + xv.w * w3.x;
        acc.y += xv.x * w0.y + xv.y * w1.y + xv.z * w2.y + xv.w * w3.y;
        acc.z += xv.x * w0.z + xv.y * w1.z + xv.z * w2.z + xv.w * w3.z;
        acc.w += xv.x * w0.w + xv.y * w1.w + xv.z * w2.w + xv.w * w3.w;
    }
    float4 bv = *(const float4*)(b + c0);
    acc.x = fmaxf(acc.x + bv.x, 0.f);
    acc.y = fmaxf(acc.y + bv.y, 0.f);
    acc.z = fmaxf(acc.z + bv.z, 0.f);
    acc.w = fmaxf(acc.w + bv.w, 0.f);
    *(float4*)(h + (long long)row * 32 + c0) = acc;
}

// 128 rows/block; thread = 16 rows x 4 cols. hp stored as FP16.
// Also computes per-head global maxes of es/ed into mxl[0..7].
template<int K>
__global__ __launch_bounds__(256) void gemm_att3(const float* __restrict__ hin,
                                                 const float* __restrict__ W,
                                                 const float* __restrict__ asrc,
                                                 const float* __restrict__ adst,
                                                 __half* __restrict__ hph,
                                                 float* __restrict__ es,
                                                 float* __restrict__ ed,
                                                 unsigned* __restrict__ mxl) {
    __shared__ float hl[128 * K];
    __shared__ unsigned lmx[8];
    int t = threadIdx.x;
    int base = blockIdx.x * 128;

    const int F4R = K / 4;
    for (int f = t; f < 128 * F4R; f += 256) {
        int row = f / F4R;
        int kq  = f % F4R;
        int gr  = base + row;
        float4 v = {0.f, 0.f, 0.f, 0.f};
        if (gr < NN) v = *(const float4*)(hin + (long long)gr * K + kq * 4);
        *(float4*)&hl[row * K + kq * 4] = v;
    }
    if (t < 8) lmx[t] = 0u;
    __syncthreads();

    int cg = t & 31, c0 = cg * 4;
    int rq = t >> 5, r0 = rq * 16;
    float4 acc[16];
    #pragma unroll
    for (int i = 0; i < 16; ++i) acc[i] = make_float4(0.f, 0.f, 0.f, 0.f);

    for (int k4 = 0; k4 < K / 4; ++k4) {
        float4 w0 = *(const float4*)(W + (k4 * 4 + 0) * 128 + c0);
        float4 w1 = *(const float4*)(W + (k4 * 4 + 1) * 128 + c0);
        float4 w2 = *(const float4*)(W + (k4 * 4 + 2) * 128 + c0);
        float4 w3 = *(const float4*)(W + (k4 * 4 + 3) * 128 + c0);
        #pragma unroll
        for (int i = 0; i < 16; ++i) {
            float4 hv = *(const float4*)&hl[(r0 + i) * K + k4 * 4];
            acc[i].x += hv.x * w0.x + hv.y * w1.x + hv.z * w2.x + hv.w * w3.x;
            acc[i].y += hv.x * w0.y + hv.y * w1.y + hv.z * w2.y + hv.w * w3.y;
            acc[i].z += hv.x * w0.z + hv.y * w1.z + hv.z * w2.z + hv.w * w3.z;
            acc[i].w += hv.x * w0.w + hv.y * w1.w + hv.z * w2.w + hv.w * w3.w;
        }
    }

    int head = cg >> 3;
    int d0 = (cg & 7) * 4;
    float4 as4 = *(const float4*)(asrc + head * 32 + d0);
    float4 ad4 = *(const float4*)(adst + head * 32 + d0);
    float smax = -1e30f, dmax = -1e30f;
    #pragma unroll
    for (int i = 0; i < 16; ++i) {
        int gr = base + r0 + i;
        if (gr >= NN) break;
        __half2 p0 = __floats2half2_rn(acc[i].x, acc[i].y);
        __half2 p1 = __floats2half2_rn(acc[i].z, acc[i].w);
        uint2 pk;
        pk.x = *(unsigned*)&p0;
        pk.y = *(unsigned*)&p1;
        *(uint2*)(hph + (long long)gr * 128 + c0) = pk;
        float ps = acc[i].x * as4.x + acc[i].y * as4.y + acc[i].z * as4.z + acc[i].w * as4.w;
        float pd = acc[i].x * ad4.x + acc[i].y * ad4.y + acc[i].z * ad4.z + acc[i].w * ad4.w;
        for (int off = 1; off < 8; off <<= 1) {
            ps += __shfl_xor(ps, off, 8);
            pd += __shfl_xor(pd, off, 8);
        }
        if ((cg & 7) == 0) {
            es[gr * 4 + head] = ps;
            ed[gr * 4 + head] = pd;
            smax = fmaxf(smax, ps);
            dmax = fmaxf(dmax, pd);
        }
    }
    if ((cg & 7) == 0) {
        atomicMax(&lmx[head], enc_f32(smax));
        atomicMax(&lmx[4 + head], enc_f32(dmax));
    }
    __syncthreads();
    if (t < 8) atomicMax(mxl + t, lmx[t]);
}

// ================== CSR build via 2-level bucket sort (once) ==================

// histogram of coarse buckets (dst>>9)
__global__ __launch_bounds__(256) void bucket_hist(const int* __restrict__ ei,
                                                   int* __restrict__ bhist) {
    __shared__ int lh[NBK];
    int t = threadIdx.x;
    for (int i = t; i < NBK; i += 256) lh[i] = 0;
    __syncthreads();
    for (long long e = (long long)blockIdx.x * 256 + t; e < ET; e += (long long)gridDim.x * 256) {
        int dst = (e < NE) ? ei[NE + e] : (int)(e - NE);
        atomicAdd(&lh[dst >> 9], 1);
    }
    __syncthreads();
    for (int i = t; i < NBK; i += 256) if (lh[i]) atomicAdd(&bhist[i], lh[i]);
}

// exclusive scan of 196 bucket counts -> bbase[197]; init cursors
__global__ __launch_bounds__(256) void bucket_scan(const int* __restrict__ bhist,
                                                   int* __restrict__ bbase,
                                                   int* __restrict__ bcur) {
    __shared__ int ls[256];
    int t = threadIdx.x;
    int v = (t < NBK) ? bhist[t] : 0;
    ls[t] = v;
    __syncthreads();
    for (int off = 1; off < 256; off <<= 1) {
        int u = (t >= off) ? ls[t - off] : 0;
        __syncthreads();
        ls[t] += u;
        __syncthreads();
    }
    if (t < NBK) { int b0 = ls[t] - v; bbase[t] = b0; bcur[t] = b0; }
    if (t == 0) bbase[NBK] = ET;
}

// coarse scatter: block reserves one contiguous run per bucket -> block-owned lines
__global__ __launch_bounds__(256) void bucket_scatter(const int* __restrict__ ei,
                                                      int* __restrict__ bcur,
                                                      unsigned* __restrict__ brec) {
    __shared__ int lcnt[NBK];
    __shared__ int lbase[NBK];
    int t = threadIdx.x;
    long long e0 = (long long)blockIdx.x * EPB;
    for (int i = t; i < NBK; i += 256) lcnt[i] = 0;
    __syncthreads();
    for (int j = 0; j < EPB / 256; ++j) {
        long long e = e0 + j * 256 + t;
        if (e < ET) {
            int dst = (e < NE) ? ei[NE + e] : (int)(e - NE);
            atomicAdd(&lcnt[dst >> 9], 1);
        }
    }
    __syncthreads();
    for (int i = t; i < NBK; i += 256) {
        int c = lcnt[i];
        lbase[i] = c ? atomicAdd(&bcur[i], c) : 0;
        lcnt[i] = 0;                        // reuse as local cursor
    }
    __syncthreads();
    for (int j = 0; j < EPB / 256; ++j) {
        long long e = e0 + j * 256 + t;
        if (e < ET) {
            int src, dst;
            if (e < NE) { src = ei[e]; dst = ei[NE + e]; }
            else        { src = dst = (int)(e - NE); }
            int b = dst >> 9;
            int off = atomicAdd(&lcnt[b], 1);
            brec[lbase[b] + off] = ((unsigned)(dst & 511) << 17) | (unsigned)src;
        }
    }
}

// fine CSR per bucket, built in LDS, streamed out coalesced
__global__ __launch_bounds__(256) void bucket_csr(const unsigned* __restrict__ brec,
                                                  const int* __restrict__ bbase,
                                                  int* __restrict__ row_ptr,
                                                  int* __restrict__ col) {
    __shared__ int ldeg[BKW];
    __shared__ int lrp[BKW + 1];
    __shared__ int lcur[BKW];
    __shared__ int ls[256];
    __shared__ int lcol[LCOL_CAP];
    int t = threadIdx.x, b = blockIdx.x;
    int rbeg = bbase[b], rend = bbase[b + 1];
    int cnt = rend - rbeg;
    for (int i = t; i < BKW; i += 256) ldeg[i] = 0;
    __syncthreads();
    for (int i = t; i < cnt; i += 256) {
        unsigned r = brec[rbeg + i];
        atomicAdd(&ldeg[r >> 17], 1);
    }
    __syncthreads();
    int a0 = ldeg[2 * t], a1 = ldeg[2 * t + 1];
    int pl = a0 + a1;
    ls[t] = pl;
    __syncthreads();
    for (int off = 1; off < 256; off <<= 1) {
        int u = (t >= off) ? ls[t - off] : 0;
        __syncthreads();
        ls[t] += u;
        __syncthreads();
    }
    int eb = ls[t] - pl;
    lrp[2 * t] = eb;
    lrp[2 * t + 1] = eb + a0;
    lcur[2 * t] = eb;
    lcur[2 * t + 1] = eb + a0;
    if (t == 255) lrp[BKW] = ls[255];
    __syncthreads();
    // row_ptr for this bucket's nodes (inclusive upper edge handled naturally)
    int gn0 = b * BKW;
    int nnb = min(BKW, NN - gn0);
    for (int i = t; i <= nnb; i += 256) row_ptr[gn0 + i] = rbeg + lrp[i];
    // fine scatter into LDS
    for (int i = t; i < cnt; i += 256) {
        unsigned r = brec[rbeg + i];
        int pos = atomicAdd(&lcur[r >> 17], 1);
        lcol[pos] = (int)(r & 0x1FFFFu);
    }
    __syncthreads();
    for (int i = t; i < cnt; i += 256) col[rbeg + i] = lcol[i];
}

// ==================== single-pass softmax-aggregate (fp16 gather) ====================
__global__ __launch_bounds__(256) void gat_aggregate3(
        const int* __restrict__ row_ptr, const int* __restrict__ col,
        const float* __restrict__ es, const float* __restrict__ ed,
        const unsigned* __restrict__ mx, const __half* __restrict__ hph,
        const float* __restrict__ b, float* __restrict__ out) {
    int tid = blockIdx.x * 256 + threadIdx.x;
    int n = tid >> 4;
    int t = tid & 15;
    if (n >= NN) return;
    int head = t >> 2;
    int beg = row_ptr[n], end = row_ptr[n + 1];

    float Craw = dec_f32(mx[head]) + dec_f32(mx[4 + head]);
    float C = Craw > 0.f ? Craw : 0.2f * Craw;
    float edv = ed[n * 4 + head];

    float acc[8] = {0.f, 0.f, 0.f, 0.f, 0.f, 0.f, 0.f, 0.f};
    float ws = 0.f;
    const __half* hb = hph + (long long)t * 8;

    int i = beg;
    for (; i + 3 < end; i += 4) {
        int s0 = col[i], s1 = col[i + 1], s2 = col[i + 2], s3 = col[i + 3];
        float l0 = es[s0 * 4 + head] + edv;
        float l1 = es[s1 * 4 + head] + edv;
        float l2 = es[s2 * 4 + head] + edv;
        float l3 = es[s3 * 4 + head] + edv;
        uint4 g0 = *(const uint4*)(hb + (long long)s0 * 128);
        uint4 g1 = *(const uint4*)(hb + (long long)s1 * 128);
        uint4 g2 = *(const uint4*)(hb + (long long)s2 * 128);
        uint4 g3 = *(const uint4*)(hb + (long long)s3 * 128);
        l0 = l0 > 0.f ? l0 : 0.2f * l0;
        l1 = l1 > 0.f ? l1 : 0.2f * l1;
        l2 = l2 > 0.f ? l2 : 0.2f * l2;
        l3 = l3 > 0.f ? l3 : 0.2f * l3;
        float w0 = __expf(l0 - C);
        float w1 = __expf(l1 - C);
        float w2 = __expf(l2 - C);
        float w3 = __expf(l3 - C);
        ws += (w0 + w1) + (w2 + w3);
        float2 f;
        f = __half22float2(*(__half2*)&g0.x); acc[0] += w0 * f.x; acc[1] += w0 * f.y;
        f = __half22float2(*(__half2*)&g0.y); acc[2] += w0 * f.x; acc[3] += w0 * f.y;
        f = __half22float2(*(__half2*)&g0.z); acc[4] += w0 * f.x; acc[5] += w0 * f.y;
        f = __half22float2(*(__half2*)&g0.w); acc[6] += w0 * f.x; acc[7] += w0 * f.y;
        f = __half22float2(*(__half2*)&g1.x); acc[0] += w1 * f.x; acc[1] += w1 * f.y;
        f = __half22float2(*(__half2*)&g1.y); acc[2] += w1 * f.x; acc[3] += w1 * f.y;
        f = __half22float2(*(__half2*)&g1.z); acc[4] += w1 * f.x; acc[5] += w1 * f.y;
        f = __half22float2(*(__half2*)&g1.w); acc[6] += w1 * f.x; acc[7] += w1 * f.y;
        f = __half22float2(*(__half2*)&g2.x); acc[0] += w2 * f.x; acc[1] += w2 * f.y;
        f = __half22float2(*(__half2*)&g2.y); acc[2] += w2 * f.x; acc[3] += w2 * f.y;
        f = __half22float2(*(__half2*)&g2.z); acc[4] += w2 * f.x; acc[5] += w2 * f.y;
        f = __half22float2(*(__half2*)&g2.w); acc[6] += w2 * f.x; acc[7] += w2 * f.y;
        f = __half22float2(*(__half2*)&g3.x); acc[0] += w3 * f.x; acc[1] += w3 * f.y;
        f = __half22float2(*(__half2*)&g3.y); acc[2] += w3 * f.x; acc[3] += w3 * f.y;
        f = __half22float2(*(__half2*)&g3.z); acc[4] += w3 * f.x; acc[5] += w3 * f.y;
        f = __half22float2(*(__half2*)&g3.w); acc[6] += w3 * f.x; acc[7] += w3 * f.y;
    }
    for (; i < end; ++i) {
        int s = col[i];
        float lv = es[s * 4 + head] + edv;
        lv = lv > 0.f ? lv : 0.2f * lv;
        float w = __expf(lv - C);
        ws += w;
        uint4 g = *(const uint4*)(hb + (long long)s * 128);
        float2 f;
        f = __half22float2(*(__half2*)&g.x); acc[0] += w * f.x; acc[1] += w * f.y;
        f = __half22float2(*(__half2*)&g.y); acc[2] += w * f.x; acc[3] += w * f.y;
        f = __half22float2(*(__half2*)&g.z); acc[4] += w * f.x; acc[5] += w * f.y;
        f = __half22float2(*(__half2*)&g.w); acc[6] += w * f.x; acc[7] += w * f.y;
    }
    float sv = ws + 1e-16f;
    float4 b0 = *(const float4*)(b + t * 8);
    float4 b1 = *(const float4*)(b + t * 8 + 4);
    float4 v0, v1;
    v0.x = acc[0] / sv + b0.x; v0.y = acc[1] / sv + b0.y;
    v0.z = acc[2] / sv + b0.z; v0.w = acc[3] / sv + b0.w;
    v1.x = acc[4] / sv + b1.x; v1.y = acc[5] / sv + b1.y;
    v1.z = acc[6] / sv + b1.z; v1.w = acc[7] / sv + b1.w;
    v0.x = v0.x > 0.f ? v0.x : expm1f(v0.x);
    v0.y = v0.y > 0.f ? v0.y : expm1f(v0.y);
    v0.z = v0.z > 0.f ? v0.z : expm1f(v0.z);
    v0.w = v0.w > 0.f ? v0.w : expm1f(v0.w);
    v1.x = v1.x > 0.f ? v1.x : expm1f(v1.x);
    v1.y = v1.y > 0.f ? v1.y : expm1f(v1.y);
    v1.z = v1.z > 0.f ? v1.z : expm1f(v1.z);
    v1.w = v1.w > 0.f ? v1.w : expm1f(v1.w);
    *(float4*)(out + (long long)n * 128 + t * 8) = v0;
    *(float4*)(out + (long long)n * 128 + t * 8 + 4) = v1;
}

// ============================ host ============================

extern "C" void kernel_launch(void* const* d_in, const int* in_sizes, int n_in,
                              void* d_out, int out_size, void* d_ws, size_t ws_size,
                              hipStream_t stream) {
    const float* x    = (const float*)d_in[0];
    const int*   ei   = (const int*)d_in[1];
    const float* W_in = (const float*)d_in[2];
    const float* b_in = (const float*)d_in[3];
    const float* W[3]  = {(const float*)d_in[4], (const float*)d_in[8],  (const float*)d_in[12]};
    const float* As[3] = {(const float*)d_in[5], (const float*)d_in[9],  (const float*)d_in[13]};
    const float* Ad[3] = {(const float*)d_in[6], (const float*)d_in[10], (const float*)d_in[14]};
    const float* Bs[3] = {(const float*)d_in[7], (const float*)d_in[11], (const float*)d_in[15]};

    // workspace layout (~55 MB); accb aliases d_out
    float*  h0     = (float*)d_ws;                      // NN*32 f32
    __half* hph    = (__half*)(h0 + (size_t)NN * 32);   // NN*128 f16
    float*  es     = (float*)(hph + (size_t)NN * 128);  // NN*4
    float*  ed     = es + (size_t)NN * 4;               // NN*4
    int*    row_ptr= (int*)(ed + (size_t)NN * 4);       // NN+1
    int*    bhist  = row_ptr + (NN + 1);                // NBK
    int*    bbase  = bhist + NBK;                       // NBK+1
    int*    bcur   = bbase + (NBK + 1);                 // NBK
    unsigned* mx   = (unsigned*)(bcur + NBK);           // 24 (8 per layer)
    unsigned* brec = (unsigned*)(mx + 24);              // ET
    int*    colb   = (int*)(brec + ET);                 // ET
    float*  accb   = (float*)d_out;                     // NN*128 f32

    // ---- CSR build via bucket sort (graph is static across layers) ----
    hipMemsetAsync(bhist, 0, NBK * sizeof(int), stream);
    hipMemsetAsync(mx, 0, 24 * sizeof(unsigned), stream);
    bucket_hist<<<512, 256, 0, stream>>>(ei, bhist);
    bucket_scan<<<1, 256, 0, stream>>>(bhist, bbase, bcur);
    bucket_scatter<<<(ET + EPB - 1) / EPB, 256, 0, stream>>>(ei, bcur, brec);
    bucket_csr<<<NBK, 256, 0, stream>>>(brec, bbase, row_ptr, colb);

    lin_relu2<<<3125, 256, 0, stream>>>(x, W_in, b_in, h0);

    const float* in = h0;
    for (int l = 0; l < 3; ++l) {
        if (l == 0)
            gemm_att3<32><<<782, 256, 0, stream>>>(in, W[0], As[0], Ad[0], hph, es, ed, mx);
        else
            gemm_att3<128><<<782, 256, 0, stream>>>(in, W[l], As[l], Ad[l], hph, es, ed, mx + l * 8);
        gat_aggregate3<<<6250, 256, 0, stream>>>(row_ptr, colb, es, ed, mx + l * 8, hph, Bs[l], accb);
        in = accb;
    }
}